// Round 7
// baseline (266.226 us; speedup 1.0000x reference)
//
#include <hip/hip_runtime.h>

#define H 1024
#define W 1024
#define K 11
#define RAD 5
#define ROWS 32              /* output rows per block strip */
#define NIN (ROWS + K - 1)   /* 42 input rows per strip */
#define BW 256               /* columns per block (1 col/thread) */

typedef float v2f __attribute__((ext_vector_type(2)));

__global__ void zero_out_kernel(float* out) {
    if (threadIdx.x == 0) out[0] = 0.0f;
}

__device__ __forceinline__ float4 ld4u(const float* p) {
    float4 v;
    __builtin_memcpy(&v, p, sizeof(float4));
    return v;
}

__device__ __forceinline__ v2f pkfma(v2f a, v2f b, v2f c) {
    return __builtin_elementwise_fma(a, b, c);
}

template<bool CFAST>
__device__ __forceinline__ void load_row(const float* __restrict__ r1,
                                         const float* __restrict__ r2,
                                         int col, float* x, float* y) {
    if (CFAST) {
        const float* a1 = r1 + (col - RAD);
        const float* a2 = r2 + (col - RAD);
        float4 v0 = ld4u(a1), v1 = ld4u(a1 + 4), v2 = ld4u(a1 + 8);
        float4 u0 = ld4u(a2), u1 = ld4u(a2 + 4), u2 = ld4u(a2 + 8);
        x[0]=v0.x; x[1]=v0.y; x[2]=v0.z; x[3]=v0.w;
        x[4]=v1.x; x[5]=v1.y; x[6]=v1.z; x[7]=v1.w;
        x[8]=v2.x; x[9]=v2.y; x[10]=v2.z; x[11]=v2.w;
        y[0]=u0.x; y[1]=u0.y; y[2]=u0.z; y[3]=u0.w;
        y[4]=u1.x; y[5]=u1.y; y[6]=u1.z; y[7]=u1.w;
        y[8]=u2.x; y[9]=u2.y; y[10]=u2.z; y[11]=u2.w;
    } else {
        #pragma unroll
        for (int m = 0; m < 12; ++m) {
            const int gc = col - RAD + m;
            const bool ok = (unsigned)gc < (unsigned)W;
            x[m] = ok ? r1[gc] : 0.0f;
            y[m] = ok ? r2[gc] : 0.0f;
        }
    }
}

template<bool CFAST, bool RFAST>
__device__ __forceinline__ float run_strip(const float* __restrict__ p1,
                                           const float* __restrict__ p2,
                                           int col, int rin0, const float* gw) {
    // 4-plane ring: rmu={mu_x,mu_y}, rsv={Sxx+Syy, Sxy}. 44 floats, static idx.
    v2f rmu[K], rsv[K];
    float acc = 0.0f;

    // Software pipeline: nx/ny hold the NEXT row's 12-col windows.
    float nx[12], ny[12];
    {
        const int rr = min(max(rin0, 0), H - 1);
        load_row<CFAST>(p1 + (size_t)rr * W, p2 + (size_t)rr * W, col, nx, ny);
    }

    for (int base = 0; base < NIN; base += K) {
        #pragma unroll
        for (int p = 0; p < K; ++p) {
            const int i = base + p;
            if (i < NIN) {
                // Consume prefetched row (register renames after unroll).
                float x[12], y[12];
                #pragma unroll
                for (int m = 0; m < 12; ++m) { x[m] = nx[m]; y[m] = ny[m]; }

                // Prefetch row i+1 (clamped; last one is harmless overrun).
                {
                    const int rr = min(max(rin0 + i + 1, 0), H - 1);
                    load_row<CFAST>(p1 + (size_t)rr * W, p2 + (size_t)rr * W,
                                    col, nx, ny);
                }

                // ---- Horizontal 11-tap, tap-paired packed fp32 ----
                v2f amx = {0.f,0.f}, amy = {0.f,0.f};
                v2f aq  = {0.f,0.f}, axy = {0.f,0.f};
                #pragma unroll
                for (int e = 0; e < 5; ++e) {
                    v2f w2 = { gw[2*e], gw[2*e+1] };
                    v2f xp = { x[2*e], x[2*e+1] };
                    v2f yp = { y[2*e], y[2*e+1] };
                    v2f wxp = w2 * xp;
                    v2f wyp = w2 * yp;
                    amx += wxp;
                    amy += wyp;
                    aq  = pkfma(wxp, xp, aq);   // Sxx part
                    aq  = pkfma(wyp, yp, aq);   // +Syy part
                    axy = pkfma(wxp, yp, axy);
                }
                const float twx = gw[10] * x[10];
                const float twy = gw[10] * y[10];
                const float hmx = (amx.x + amx.y) + twx;
                const float hmy = (amy.x + amy.y) + twy;
                const float hq  = fmaf(twx, x[10], fmaf(twy, y[10], aq.x + aq.y));
                const float hxy = fmaf(twx, y[10], axy.x + axy.y);

                if (RFAST) {
                    rmu[p] = (v2f){ hmx, hmy };
                    rsv[p] = (v2f){ hq,  hxy };
                } else {
                    const int r = rin0 + i;
                    const float s = ((unsigned)r < (unsigned)H) ? 1.0f : 0.0f;
                    v2f s2 = { s, s };
                    rmu[p] = s2 * (v2f){ hmx, hmy };
                    rsv[p] = s2 * (v2f){ hq,  hxy };
                }

                // ---- Vertical 11-tap over the ring + SSIM, once primed ----
                if (i >= K - 1) {
                    v2f mu = {0.f,0.f}, sv = {0.f,0.f};
                    #pragma unroll
                    for (int j = 0; j < K; ++j) {
                        const int sl = (p + 1 + j) % K;   // static after unroll
                        v2f w2 = { gw[j], gw[j] };
                        mu = pkfma(w2, rmu[sl], mu);
                        sv = pkfma(w2, rsv[sl], sv);
                    }
                    v2f m2 = mu * mu;                     // {mx2, my2}
                    const float mxy  = mu.x * mu.y;
                    const float musq = m2.x + m2.y;       // mx2+my2
                    const float sg   = sv.x - musq;       // sx2+sy2
                    const float sxyv = sv.y - mxy;
                    const float num = fmaf(2.0f, mxy,  1e-4f) * fmaf(2.0f, sxyv, 9e-4f);
                    const float den = (musq + 1e-4f) * (sg + 9e-4f);
                    acc += num * __builtin_amdgcn_rcpf(den);
                }
            }
        }
    }
    return acc;
}

__launch_bounds__(256, 2)
__global__ void ssim_kernel(const float* __restrict__ img1,
                            const float* __restrict__ img2,
                            const float* __restrict__ kern,
                            float* __restrict__ out,
                            float inv_n) {
    __shared__ float wsum[4];

    const int tid = threadIdx.x;
    const int col = blockIdx.x * BW + tid;
    const int ry0 = blockIdx.y * ROWS;
    const int b   = blockIdx.z;

    // 1D gaussian = row sums of normalized 2D kernel (exact). Pin to SGPRs.
    float gw[K];
    #pragma unroll
    for (int t = 0; t < K; ++t) {
        float s = 0.0f;
        #pragma unroll
        for (int j = 0; j < K; ++j) s += kern[t * K + j];
        gw[t] = __int_as_float(__builtin_amdgcn_readfirstlane(__float_as_int(s)));
    }

    const float* __restrict__ p1 = img1 + (size_t)b * H * W;
    const float* __restrict__ p2 = img2 + (size_t)b * H * W;
    const int rin0 = ry0 - RAD;

    // Block-uniform row specialization; wave-uniform column specialization.
    const bool rfast = (rin0 >= 0) && (rin0 + NIN <= H);
    const bool colfast = (col >= RAD) && (col + RAD + 1 < W);
    const unsigned long long bal = __ballot(colfast);

    float acc;
    if (bal == ~0ULL) {
        acc = rfast ? run_strip<true,  true >(p1, p2, col, rin0, gw)
                    : run_strip<true,  false>(p1, p2, col, rin0, gw);
    } else {
        acc = rfast ? run_strip<false, true >(p1, p2, col, rin0, gw)
                    : run_strip<false, false>(p1, p2, col, rin0, gw);
    }

    // Wave butterfly reduce -> cross-wave via LDS -> one atomic per block.
    for (int off = 32; off > 0; off >>= 1)
        acc += __shfl_down(acc, off, 64);
    if ((tid & 63) == 0) wsum[tid >> 6] = acc;
    __syncthreads();
    if (tid == 0) {
        const float s = wsum[0] + wsum[1] + wsum[2] + wsum[3];
        atomicAdd(out, s * inv_n);
    }
}

extern "C" void kernel_launch(void* const* d_in, const int* in_sizes, int n_in,
                              void* d_out, int out_size, void* d_ws, size_t ws_size,
                              hipStream_t stream) {
    const float* img1 = (const float*)d_in[0];
    const float* img2 = (const float*)d_in[1];
    const float* kern = (const float*)d_in[2];
    float* out = (float*)d_out;

    const int B = in_sizes[0] / (H * W);
    const float inv_n = 1.0f / ((float)B * (float)H * (float)W);

    zero_out_kernel<<<dim3(1), dim3(64), 0, stream>>>(out);

    dim3 grid(W / BW, H / ROWS, B);
    ssim_kernel<<<grid, dim3(256), 0, stream>>>(img1, img2, kern, out, inv_n);
}